// Round 6
// baseline (1422.919 us; speedup 1.0000x reference)
//
#include <hip/hip_runtime.h>

typedef __attribute__((ext_vector_type(8))) _Float16 half8;
typedef __attribute__((ext_vector_type(16))) float f32x16;

#define TOK 98
#define QSCALE 0.17677669529663687f  // 1/sqrt(32)

// LDS layout in _Float16 units — three overlaid phases:
//  Phase A (staging):     XL [98][132] at 0            (x as fp16)
//  Phase B (after bar#2): VT [32][132] at 0,  QS [98][40] at 4224, KS [98][40] at 8144
//  Phase C (after bar#4): PS [98][120] at 4224         (over dead Q,K)
#define XL   0
#define XSTR 132
#define VT   0
#define VSTR 132
#define QS   4224
#define KS   8144
#define PS   4224
#define PSTR 120
#define LDSH 15984   // halves = 31968 B -> 5 blocks/CU (<= 32768)

#define BIAS_STR 112  // bias32 row stride (j dim padded 98->112)

__device__ inline half8 cvt8(float4 a, float4 b) {
    half8 r;
    r[0] = (_Float16)a.x; r[1] = (_Float16)a.y; r[2] = (_Float16)a.z; r[3] = (_Float16)a.w;
    r[4] = (_Float16)b.x; r[5] = (_Float16)b.y; r[6] = (_Float16)b.z; r[7] = (_Float16)b.w;
    return r;
}

// ---------------- Prep: weights -> fp16 fragment order; rel -> bias table ----
// qkv region  [0..49152):  idx = (((h*3+nt)*8 + kt)*64 + lane)*8 + e
// proj region [49152..65536): idx = ((nt*8 + kt)*64 + lane)*8 + e
// bias32[h][m][j] (j<98; stride 112) = rel[h][REL_IDX[m][j]]  (fp32, exact)
__global__ void prep_w(const float* __restrict__ qkv_w,
                       const float* __restrict__ proj_w,
                       const float* __restrict__ rel,
                       _Float16* __restrict__ w16,
                       float* __restrict__ bias32)
{
    int i = blockIdx.x * 256 + threadIdx.x;   // grid covers 65536 + 4*98*112
    if (i < 49152) {
        int e = i & 7, lane = (i >> 3) & 63, kt = (i >> 9) & 7;
        int g = i >> 12;                  // g = h*3 + nt, 0..11
        int h = g / 3, nt = g - 3 * h;
        int t32 = lane & 31, hf = lane >> 5;
        w16[i] = (_Float16)qkv_w[(nt * 128 + h * 32 + t32) * 128 + kt * 16 + hf * 8 + e];
    } else if (i < 65536) {
        int j = i - 49152;
        int e = j & 7, lane = (j >> 3) & 63, kt = (j >> 9) & 7, nt = j >> 12;
        int t32 = lane & 31, hf = lane >> 5;
        w16[i] = (_Float16)proj_w[(nt * 32 + t32) * 128 + kt * 16 + hf * 8 + e];
    } else if (i < 65536 + 4 * 98 * BIAS_STR) {
        int j0 = i - 65536;
        int jj = j0 % BIAS_STR;
        int t  = j0 / BIAS_STR;
        int m  = t % 98, h = t / 98;
        float v = 0.f;
        if (jj < 98) {
            int ti = m / 49,  r2 = m - 49 * ti,  hi = r2 / 7,  wi = r2 - 7 * hi;
            int tj = jj / 49, rj = jj - 49 * tj, hj = rj / 7, wj = rj - 7 * hj;
            int idx = (ti - tj + 1) * 169 + (hi - hj + 6) * 13 + (wi - wj + 6);
            v = rel[h * 507 + idx];
        }
        bias32[j0] = v;
    }
}

__global__ __launch_bounds__(256, 5) void attn_mfma(
    const float* __restrict__ x,       // [B][98][128]
    const float* __restrict__ mask,    // [L][98][98]
    const float* __restrict__ qkv_b,   // [384]
    const _Float16* __restrict__ qkv16,// fragment-ordered qkv weights
    const float* __restrict__ bias32,  // [4][98][112]
    float* __restrict__ out,           // [B][98][128] (pre-proj, fp32 path)
    _Float16* __restrict__ o16,        // [B][98][128] fp16 (ws path)
    int Lmask, int useO16)
{
    __shared__ __align__(16) _Float16 lh[LDSH];

    const int tid  = threadIdx.x;

    // XCD-bijective swizzle (grid % 8 == 0 in this problem).
    int wg = (int)blockIdx.x;
    int work;
    if ((gridDim.x & 7) == 0) {
        int cpx = gridDim.x >> 3;
        work = (wg & 7) * cpx + (wg >> 3);
    } else {
        work = wg;
    }
    const int b    = work >> 2;
    const int h    = work & 3;

    const int wv   = tid >> 6;        // wave 0..3: owns token rows [32wv, 32wv+32)
    const int lane = tid & 63;
    const int t32  = lane & 31;
    const int half = lane >> 5;

    // ---- stage x fp16 coalesced into XL ----
    for (int j = tid; j < TOK * 16; j += 256) {
        int row = j >> 4, c8 = (j & 15) << 3;
        const float* src = x + ((long)b * TOK + row) * 128 + c8;
        float4 a0 = *(const float4*)src;
        float4 a1 = *(const float4*)(src + 4);
        *(half8*)&lh[XL + row * XSTR + c8] = cvt8(a0, a1);
    }
    __syncthreads();   // bar #1: XL ready

    // ---- preload A fragments (all XL reads happen here) ----
    int tok = 32 * wv + t32; if (tok > 97) tok = 97;   // clamp: dup rows discarded

    half8 af[8];
#pragma unroll
    for (int kt = 0; kt < 8; ++kt)
        af[kt] = *(const half8*)&lh[XL + tok * XSTR + kt * 16 + half * 8];

    // ---- mask + bias burst: unconditional clamped loads, issued EARLY so the
    //      latency hides under stage-1 MFMAs + stores + two barriers.
    const long mbase = (long)(b % Lmask) * (TOK * TOK);
    const int mrow0 = 32 * wv + 4 * half;

    bool jvld[4];
    float mv[4][16], bv[4][16];
#pragma unroll
    for (int nt = 0; nt < 4; ++nt) {
        int j = nt * 32 + t32;
        jvld[nt] = (j < TOK);
        int jc = jvld[nt] ? j : 97;
        const float* mc = mask + mbase + jc;
        const float* bc = bias32 + (h * 98) * BIAS_STR + jc;
#pragma unroll
        for (int reg = 0; reg < 16; ++reg) {
            int m = mrow0 + (reg & 3) + 8 * (reg >> 2);
            int mm = m > 97 ? 97 : m;
            mv[nt][reg] = mc[(long)mm * TOK];
            bv[nt][reg] = bc[mm * BIAS_STR];
        }
    }

    __syncthreads();   // bar #2: XL dead -> Q/K/Vt region may be written

    // ---------------- Stage 1: qkv slice GEMM (A regs, B fragment-coalesced) --
    const _Float16* wbase = qkv16 + (long)h * 3 * 4096 + lane * 8;  // + (nt*8+kt)*512

    f32x16 acc[3];
#pragma unroll
    for (int nt = 0; nt < 3; nt++)
#pragma unroll
        for (int i = 0; i < 16; i++) acc[nt][i] = 0.f;

#pragma unroll
    for (int kt = 0; kt < 8; ++kt) {
#pragma unroll
        for (int nt = 0; nt < 3; nt++) {
            half8 bf = *(const half8*)(wbase + (nt * 8 + kt) * 512);
            acc[nt] = __builtin_amdgcn_mfma_f32_32x32x16_f16(af[kt], bf, acc[nt], 0, 0, 0);
        }
    }

    // store Q (scaled+bias), K row-major; V transposed Vt[d][m].
    // C/D layout: col=lane&31, row=(reg&3)+8*(reg>>2)+4*half
    {
        const float qb = qkv_b[h * 32 + t32];
        const float kb = qkv_b[128 + h * 32 + t32];
        const float vb = qkv_b[256 + h * 32 + t32];
        const bool allv = (32 * wv + 31) < TOK;     // wave-uniform: rows all valid
        if (allv) {
#pragma unroll
            for (int reg = 0; reg < 16; ++reg) {
                int m = 32 * wv + (reg & 3) + 8 * (reg >> 2) + 4 * half;
                lh[QS + m * 40 + t32]   = (_Float16)((acc[0][reg] + qb) * QSCALE);
                lh[KS + m * 40 + t32]   = (_Float16)(acc[1][reg] + kb);
                lh[VT + t32 * VSTR + m] = (_Float16)(acc[2][reg] + vb);
            }
        } else {
#pragma unroll
            for (int reg = 0; reg < 16; ++reg) {
                int m = 32 * wv + (reg & 3) + 8 * (reg >> 2) + 4 * half;
                if (m < TOK) {
                    lh[QS + m * 40 + t32]   = (_Float16)((acc[0][reg] + qb) * QSCALE);
                    lh[KS + m * 40 + t32]   = (_Float16)(acc[1][reg] + kb);
                    lh[VT + t32 * VSTR + m] = (_Float16)(acc[2][reg] + vb);
                }
            }
        }
    }
    // zero Vt pad tokens 98..111 (PV k-padding) — VT region valid after bar#2
    for (int i = tid; i < 32 * 14; i += 256) {
        int d = i / 14, m = i - 14 * d;
        lh[VT + d * VSTR + 98 + m] = (_Float16)0.f;
    }

    __syncthreads();   // bar #3: Q/K/Vt visible; burst latency fully drained here

    // ---- init S accumulator with bias+mask+validity (MFMA C-input) ----------
    f32x16 sacc[4];
#pragma unroll
    for (int reg = 0; reg < 16; ++reg) {
        int m = mrow0 + (reg & 3) + 8 * (reg >> 2);
        bool mok = (m < TOK);
#pragma unroll
        for (int nt = 0; nt < 4; ++nt)
            sacc[nt][reg] = (mok && jvld[nt]) ? bv[nt][reg] + mv[nt][reg] : -1e30f;
    }

    // ---------------- Stage 2: S += Q K^T (accumulates onto bias init) -------
#pragma unroll
    for (int kk = 0; kk < 2; ++kk) {
        half8 qa = *(const half8*)&lh[QS + tok * 40 + kk * 16 + half * 8];
#pragma unroll
        for (int nt = 0; nt < 4; ++nt) {
            int kr = nt * 32 + t32; if (kr > 97) kr = 97;   // dup cols stay ~-1e30
            half8 kf = *(const half8*)&lh[KS + kr * 40 + kk * 16 + half * 8];
            sacc[nt] = __builtin_amdgcn_mfma_f32_32x32x16_f16(qa, kf, sacc[nt], 0, 0, 0);
        }
    }

    __syncthreads();   // bar #4: all Q/K reads done -> P may overlay them

    // ---------------- Stage 3: tile-max softmax ----------------
    float wm = -1e30f;
#pragma unroll
    for (int nt = 0; nt < 4; ++nt)
#pragma unroll
        for (int reg = 0; reg < 16; ++reg) wm = fmaxf(wm, sacc[nt][reg]);
    wm = fmaxf(wm, __shfl_xor(wm, 1));
    wm = fmaxf(wm, __shfl_xor(wm, 2));
    wm = fmaxf(wm, __shfl_xor(wm, 4));
    wm = fmaxf(wm, __shfl_xor(wm, 8));
    wm = fmaxf(wm, __shfl_xor(wm, 16));
    wm = fmaxf(wm, __shfl_xor(wm, 32));

#pragma unroll
    for (int nt = 0; nt < 4; ++nt) {
        int j = nt * 32 + t32;
#pragma unroll
        for (int reg = 0; reg < 16; ++reg) {
            int m = mrow0 + (reg & 3) + 8 * (reg >> 2);
            float p = __expf(sacc[nt][reg] - wm);
            if (m < TOK && j < 112) lh[PS + m * PSTR + j] = (_Float16)p; // pad cols -> exact 0
        }
    }

    // ---------------- Stage 4: O = P V ; row-sums via MFMA against ones ------
    f32x16 oacc, osum;
#pragma unroll
    for (int i = 0; i < 16; i++) { oacc[i] = 0.f; osum[i] = 0.f; }

    half8 vones;
#pragma unroll
    for (int i = 0; i < 8; ++i) vones[i] = (_Float16)1.0f;

#pragma unroll
    for (int kk = 0; kk < 7; ++kk) {
        half8 pa = *(const half8*)&lh[PS + tok * PSTR + kk * 16 + half * 8];
        half8 vf = *(const half8*)&lh[VT + t32 * VSTR + kk * 16 + half * 8];
        oacc = __builtin_amdgcn_mfma_f32_32x32x16_f16(pa, vf, oacc, 0, 0, 0);
        osum = __builtin_amdgcn_mfma_f32_32x32x16_f16(pa, vones, osum, 0, 0, 0);
    }

    const bool allv = (32 * wv + 31) < TOK;
    if (useO16) {
        _Float16* ob = o16 + ((long)b * TOK) * 128 + h * 32 + t32;
#pragma unroll
        for (int reg = 0; reg < 16; ++reg) {
            int m = mrow0 + (reg & 3) + 8 * (reg >> 2);
            float inv = __builtin_amdgcn_rcpf(osum[reg]);
            if (allv || m < TOK) ob[(long)m * 128] = (_Float16)(oacc[reg] * inv);
        }
    } else {
        float* ob = out + ((long)b * TOK) * 128 + h * 32 + t32;
#pragma unroll
        for (int reg = 0; reg < 16; ++reg) {
            int m = mrow0 + (reg & 3) + 8 * (reg >> 2);
            float inv = __builtin_amdgcn_rcpf(osum[reg]);
            if (allv || m < TOK) ob[(long)m * 128] = oacc[reg] * inv;
        }
    }
}

// ---------------- Proj GEMM: A staged in LDS, W fragment-coalesced global ---
template <bool A16>
__global__ __launch_bounds__(256, 4) void proj_mfma(
    const void* __restrict__ Ain,       // fp16 o16 or fp32 out
    const _Float16* __restrict__ w16,   // fragment-ordered proj weights
    const float* __restrict__ proj_b,   // [128]
    float* __restrict__ out,
    int totalRows)
{
    __shared__ __align__(16) _Float16 al[128 * 132];   // 33792 B -> 4 blocks/CU

    const int tid  = threadIdx.x;
    const int wv   = tid >> 6;
    const int lane = tid & 63;
    const int t32  = lane & 31;
    const int half = lane >> 5;

    // coalesced staging of this block's 128 A rows as fp16
#pragma unroll
    for (int it = 0; it < 8; ++it) {
        int j = it * 256 + tid;           // 128 rows x 16 chunks
        int row = j >> 4, c8 = (j & 15) << 3;
        long gr = (long)blockIdx.x * 128 + row;
        if (gr >= totalRows) gr = totalRows - 1;
        if (A16) {
            *(half8*)&al[row * 132 + c8] =
                *(const half8*)((const _Float16*)Ain + gr * 128 + c8);
        } else {
            const float* src = (const float*)Ain + gr * 128 + c8;
            float4 a0 = *(const float4*)src;
            float4 a1 = *(const float4*)(src + 4);
            *(half8*)&al[row * 132 + c8] = cvt8(a0, a1);
        }
    }
    __syncthreads();

    half8 af[8];
#pragma unroll
    for (int kt = 0; kt < 8; ++kt)
        af[kt] = *(const half8*)&al[(32 * wv + t32) * 132 + kt * 16 + half * 8];

    const _Float16* wb = w16 + lane * 8;   // + (nt*8+kt)*512

    f32x16 acc[4];
#pragma unroll
    for (int nt = 0; nt < 4; nt++)
#pragma unroll
        for (int i = 0; i < 16; i++) acc[nt][i] = 0.f;

#pragma unroll
    for (int kt = 0; kt < 8; ++kt) {
#pragma unroll
        for (int nt = 0; nt < 4; ++nt) {
            half8 bf = *(const half8*)(wb + (nt * 8 + kt) * 512);
            acc[nt] = __builtin_amdgcn_mfma_f32_32x32x16_f16(af[kt], bf, acc[nt], 0, 0, 0);
        }
    }

    const long rowb = (long)blockIdx.x * 128 + 32 * wv;
#pragma unroll
    for (int nt = 0; nt < 4; ++nt) {
        int co = nt * 32 + t32;
        float pb = proj_b[co];
#pragma unroll
        for (int reg = 0; reg < 16; ++reg) {
            long m = rowb + (reg & 3) + 8 * (reg >> 2) + 4 * half;
            if (m < totalRows) out[m * 128 + co] = acc[nt][reg] + pb;
        }
    }
}

extern "C" void kernel_launch(void* const* d_in, const int* in_sizes, int n_in,
                              void* d_out, int out_size, void* d_ws, size_t ws_size,
                              hipStream_t stream) {
    const float* x      = (const float*)d_in[0];
    const float* mask   = (const float*)d_in[1];
    const float* qkv_w  = (const float*)d_in[2];
    const float* qkv_b  = (const float*)d_in[3];
    const float* rel    = (const float*)d_in[4];
    const float* proj_w = (const float*)d_in[5];
    const float* proj_b = (const float*)d_in[6];
    float* out = (float*)d_out;

    const int B     = in_sizes[0] / (TOK * 128);
    const int Lmask = in_sizes[1] / (TOK * TOK);
    const int totalRows = B * TOK;

    // ws layout: w16 (65536 halves = 131072 B) | bias32 (4*98*112 f32 = 175616 B) | o16
    _Float16* w16    = (_Float16*)d_ws;
    float*    bias32 = (float*)((char*)d_ws + 131072);
    _Float16* o16    = (_Float16*)((char*)d_ws + 131072 + 175616);
    const size_t needO = 131072 + 175616 + (size_t)totalRows * 256;
    const int useO16 = (ws_size >= needO) ? 1 : 0;

    const int prepN = 65536 + 4 * 98 * BIAS_STR;
    prep_w<<<(prepN + 255) / 256, 256, 0, stream>>>(qkv_w, proj_w, rel, w16, bias32);

    attn_mfma<<<B * 4, 256, 0, stream>>>(x, mask, qkv_b, w16, bias32, out, o16,
                                         Lmask, useO16);

    const int grid = (totalRows + 127) / 128;
    if (useO16)
        proj_mfma<true><<<grid, 256, 0, stream>>>((const void*)o16, w16 + 49152,
                                                  proj_b, out, totalRows);
    else
        proj_mfma<false><<<grid, 256, 0, stream>>>((const void*)out, w16 + 49152,
                                                   proj_b, out, totalRows);
}

// Round 7
// 622.381 us; speedup vs baseline: 2.2863x; 2.2863x over previous
//
#include <hip/hip_runtime.h>

typedef __attribute__((ext_vector_type(8))) _Float16 half8;
typedef __attribute__((ext_vector_type(16))) float f32x16;

#define TOK 98
#define QSCALE 0.17677669529663687f  // 1/sqrt(32)

// LDS layout in _Float16 units — three overlaid phases:
//  Phase A (staging):     XL [98][132] at 0            (x as fp16)
//  Phase B (after bar#2): VT [32][132] at 0,  QS [98][40] at 4224, KS [98][40] at 8144
//  Phase C (after bar#4): PS [98][120] at 4224         (over dead Q,K)
#define XL   0
#define XSTR 132
#define VT   0
#define VSTR 132
#define QS   4224
#define KS   8144
#define PS   4224
#define PSTR 120
#define LDSH 15984   // halves = 31968 B (kernel total 32256 B with pad)

#define BIAS_STR 112  // bias32 row stride (j dim padded 98->112)

__device__ inline half8 cvt8(float4 a, float4 b) {
    half8 r;
    r[0] = (_Float16)a.x; r[1] = (_Float16)a.y; r[2] = (_Float16)a.z; r[3] = (_Float16)a.w;
    r[4] = (_Float16)b.x; r[5] = (_Float16)b.y; r[6] = (_Float16)b.z; r[7] = (_Float16)b.w;
    return r;
}

// ---------------- Prep: weights -> fp16 fragment order; rel -> bias table ----
// qkv region  [0..49152):  idx = (((h*3+nt)*8 + kt)*64 + lane)*8 + e
// proj region [49152..65536): idx = ((nt*8 + kt)*64 + lane)*8 + e
// bias32[h][m][j] (j<98; stride 112) = rel[h][REL_IDX[m][j]]  (fp32, exact)
__global__ void prep_w(const float* __restrict__ qkv_w,
                       const float* __restrict__ proj_w,
                       const float* __restrict__ rel,
                       _Float16* __restrict__ w16,
                       float* __restrict__ bias32)
{
    int i = blockIdx.x * 256 + threadIdx.x;   // grid covers 65536 + 4*98*112
    if (i < 49152) {
        int e = i & 7, lane = (i >> 3) & 63, kt = (i >> 9) & 7;
        int g = i >> 12;                  // g = h*3 + nt, 0..11
        int h = g / 3, nt = g - 3 * h;
        int t32 = lane & 31, hf = lane >> 5;
        w16[i] = (_Float16)qkv_w[(nt * 128 + h * 32 + t32) * 128 + kt * 16 + hf * 8 + e];
    } else if (i < 65536) {
        int j = i - 49152;
        int e = j & 7, lane = (j >> 3) & 63, kt = (j >> 9) & 7, nt = j >> 12;
        int t32 = lane & 31, hf = lane >> 5;
        w16[i] = (_Float16)proj_w[(nt * 32 + t32) * 128 + kt * 16 + hf * 8 + e];
    } else if (i < 65536 + 4 * 98 * BIAS_STR) {
        int j0 = i - 65536;
        int jj = j0 % BIAS_STR;
        int t  = j0 / BIAS_STR;
        int m  = t % 98, h = t / 98;
        float v = 0.f;
        if (jj < 98) {
            int ti = m / 49,  r2 = m - 49 * ti,  hi = r2 / 7,  wi = r2 - 7 * hi;
            int tj = jj / 49, rj = jj - 49 * tj, hj = rj / 7, wj = rj - 7 * hj;
            int idx = (ti - tj + 1) * 169 + (hi - hj + 6) * 13 + (wi - wj + 6);
            v = rel[h * 507 + idx];
        }
        bias32[j0] = v;
    }
}

__global__ __launch_bounds__(256, 4) void attn_mfma(
    const float* __restrict__ x,       // [B][98][128]
    const float* __restrict__ mask,    // [L][98][98]
    const float* __restrict__ qkv_b,   // [384]
    const _Float16* __restrict__ qkv16,// fragment-ordered qkv weights
    const float* __restrict__ bias32,  // [4][98][112]
    float* __restrict__ out,           // [B][98][128] (pre-proj, fp32 path)
    _Float16* __restrict__ o16,        // [B][98][128] fp16 (ws path)
    int Lmask, int useO16)
{
    __shared__ __align__(16) _Float16 lh[LDSH];

    const int tid  = threadIdx.x;

    // XCD-bijective swizzle (grid % 8 == 0 in this problem).
    int wg = (int)blockIdx.x;
    int work;
    if ((gridDim.x & 7) == 0) {
        int cpx = gridDim.x >> 3;
        work = (wg & 7) * cpx + (wg >> 3);
    } else {
        work = wg;
    }
    const int b    = work >> 2;
    const int h    = work & 3;

    const int wv   = tid >> 6;        // wave 0..3: owns token rows [32wv, 32wv+32)
    const int lane = tid & 63;
    const int t32  = lane & 31;
    const int half = lane >> 5;

    // ---- stage x fp16 coalesced into XL ----
    for (int j = tid; j < TOK * 16; j += 256) {
        int row = j >> 4, c8 = (j & 15) << 3;
        const float* src = x + ((long)b * TOK + row) * 128 + c8;
        float4 a0 = *(const float4*)src;
        float4 a1 = *(const float4*)(src + 4);
        *(half8*)&lh[XL + row * XSTR + c8] = cvt8(a0, a1);
    }
    __syncthreads();   // bar #1: XL ready

    // ---- preload A fragments (all XL reads happen here) ----
    int tok = 32 * wv + t32; if (tok > 97) tok = 97;   // clamp: dup rows discarded

    half8 af[8];
#pragma unroll
    for (int kt = 0; kt < 8; ++kt)
        af[kt] = *(const half8*)&lh[XL + tok * XSTR + kt * 16 + half * 8];

    __syncthreads();   // bar #2: XL dead -> Q/K/Vt region may be written

    // ---------------- Stage 1: qkv slice GEMM (A regs, B fragment-coalesced) --
    const _Float16* wbase = qkv16 + (long)h * 3 * 4096 + lane * 8;  // + (nt*8+kt)*512

    f32x16 acc[3];
#pragma unroll
    for (int nt = 0; nt < 3; nt++)
#pragma unroll
        for (int i = 0; i < 16; i++) acc[nt][i] = 0.f;

#pragma unroll
    for (int kt = 0; kt < 8; ++kt) {
#pragma unroll
        for (int nt = 0; nt < 3; nt++) {
            half8 bf = *(const half8*)(wbase + (nt * 8 + kt) * 512);
            acc[nt] = __builtin_amdgcn_mfma_f32_32x32x16_f16(af[kt], bf, acc[nt], 0, 0, 0);
        }
    }

    // store Q (scaled+bias), K row-major; V transposed Vt[d][m].
    // C/D layout: col=lane&31, row=(reg&3)+8*(reg>>2)+4*half
    {
        const float qb = qkv_b[h * 32 + t32];
        const float kb = qkv_b[128 + h * 32 + t32];
        const float vb = qkv_b[256 + h * 32 + t32];
        const bool allv = (32 * wv + 31) < TOK;     // wave-uniform: rows all valid
        if (allv) {
#pragma unroll
            for (int reg = 0; reg < 16; ++reg) {
                int m = 32 * wv + (reg & 3) + 8 * (reg >> 2) + 4 * half;
                lh[QS + m * 40 + t32]   = (_Float16)((acc[0][reg] + qb) * QSCALE);
                lh[KS + m * 40 + t32]   = (_Float16)(acc[1][reg] + kb);
                lh[VT + t32 * VSTR + m] = (_Float16)(acc[2][reg] + vb);
            }
        } else {
#pragma unroll
            for (int reg = 0; reg < 16; ++reg) {
                int m = 32 * wv + (reg & 3) + 8 * (reg >> 2) + 4 * half;
                if (m < TOK) {
                    lh[QS + m * 40 + t32]   = (_Float16)((acc[0][reg] + qb) * QSCALE);
                    lh[KS + m * 40 + t32]   = (_Float16)(acc[1][reg] + kb);
                    lh[VT + t32 * VSTR + m] = (_Float16)(acc[2][reg] + vb);
                }
            }
        }
    }
    // zero Vt pad tokens 98..111 (PV k-padding) — VT region valid after bar#2
    for (int i = tid; i < 32 * 14; i += 256) {
        int d = i / 14, m = i - 14 * d;
        lh[VT + d * VSTR + 98 + m] = (_Float16)0.f;
    }

    // ---- mask+bias burst: unconditional clamped loads, SUMMED AT LOAD so
    //      only 64 f32 stay live (round-6 spill fix). Latency hides under
    //      the bar#3 wait.
    const long mbase = (long)(b % Lmask) * (TOK * TOK);
    const int mrow0 = 32 * wv + 4 * half;

    bool jvld[4];
    float sv[4][16];
#pragma unroll
    for (int nt = 0; nt < 4; ++nt) {
        int j = nt * 32 + t32;
        jvld[nt] = (j < TOK);
        int jc = jvld[nt] ? j : 97;
        const float* mc = mask + mbase + jc;
        const float* bc = bias32 + (h * 98) * BIAS_STR + jc;
#pragma unroll
        for (int reg = 0; reg < 16; ++reg) {
            int m = mrow0 + (reg & 3) + 8 * (reg >> 2);
            int mm = m > 97 ? 97 : m;
            sv[nt][reg] = mc[(long)mm * TOK] + bc[mm * BIAS_STR];
        }
    }

    __syncthreads();   // bar #3: Q/K/Vt visible; burst latency drains here

    // ---- init S accumulator with summed bias+mask+validity (MFMA C-input) ---
    f32x16 sacc[4];
#pragma unroll
    for (int reg = 0; reg < 16; ++reg) {
        int m = mrow0 + (reg & 3) + 8 * (reg >> 2);
        bool mok = (m < TOK);
#pragma unroll
        for (int nt = 0; nt < 4; ++nt)
            sacc[nt][reg] = (mok && jvld[nt]) ? sv[nt][reg] : -1e30f;
    }

    // ---------------- Stage 2: S += Q K^T (accumulates onto bias init) -------
#pragma unroll
    for (int kk = 0; kk < 2; ++kk) {
        half8 qa = *(const half8*)&lh[QS + tok * 40 + kk * 16 + half * 8];
#pragma unroll
        for (int nt = 0; nt < 4; ++nt) {
            int kr = nt * 32 + t32; if (kr > 97) kr = 97;   // dup cols stay ~-1e30
            half8 kf = *(const half8*)&lh[KS + kr * 40 + kk * 16 + half * 8];
            sacc[nt] = __builtin_amdgcn_mfma_f32_32x32x16_f16(qa, kf, sacc[nt], 0, 0, 0);
        }
    }

    __syncthreads();   // bar #4: all Q/K reads done -> P may overlay them

    // ---------------- Stage 3: tile-max softmax ----------------
    float wm = -1e30f;
#pragma unroll
    for (int nt = 0; nt < 4; ++nt)
#pragma unroll
        for (int reg = 0; reg < 16; ++reg) wm = fmaxf(wm, sacc[nt][reg]);
    wm = fmaxf(wm, __shfl_xor(wm, 1));
    wm = fmaxf(wm, __shfl_xor(wm, 2));
    wm = fmaxf(wm, __shfl_xor(wm, 4));
    wm = fmaxf(wm, __shfl_xor(wm, 8));
    wm = fmaxf(wm, __shfl_xor(wm, 16));
    wm = fmaxf(wm, __shfl_xor(wm, 32));

#pragma unroll
    for (int nt = 0; nt < 4; ++nt) {
        int j = nt * 32 + t32;
#pragma unroll
        for (int reg = 0; reg < 16; ++reg) {
            int m = mrow0 + (reg & 3) + 8 * (reg >> 2);
            float p = __expf(sacc[nt][reg] - wm);
            if (m < TOK && j < 112) lh[PS + m * PSTR + j] = (_Float16)p; // pad cols -> exact 0
        }
    }

    // ---------------- Stage 4: O = P V ; row-sums via MFMA against ones ------
    f32x16 oacc, osum;
#pragma unroll
    for (int i = 0; i < 16; i++) { oacc[i] = 0.f; osum[i] = 0.f; }

    half8 vones;
#pragma unroll
    for (int i = 0; i < 8; ++i) vones[i] = (_Float16)1.0f;

#pragma unroll
    for (int kk = 0; kk < 7; ++kk) {
        half8 pa = *(const half8*)&lh[PS + tok * PSTR + kk * 16 + half * 8];
        half8 vf = *(const half8*)&lh[VT + t32 * VSTR + kk * 16 + half * 8];
        oacc = __builtin_amdgcn_mfma_f32_32x32x16_f16(pa, vf, oacc, 0, 0, 0);
        osum = __builtin_amdgcn_mfma_f32_32x32x16_f16(pa, vones, osum, 0, 0, 0);
    }

    const bool allv = (32 * wv + 31) < TOK;
    if (useO16) {
        _Float16* ob = o16 + ((long)b * TOK) * 128 + h * 32 + t32;
#pragma unroll
        for (int reg = 0; reg < 16; ++reg) {
            int m = mrow0 + (reg & 3) + 8 * (reg >> 2);
            float inv = __builtin_amdgcn_rcpf(osum[reg]);
            if (allv || m < TOK) ob[(long)m * 128] = (_Float16)(oacc[reg] * inv);
        }
    } else {
        float* ob = out + ((long)b * TOK) * 128 + h * 32 + t32;
#pragma unroll
        for (int reg = 0; reg < 16; ++reg) {
            int m = mrow0 + (reg & 3) + 8 * (reg >> 2);
            float inv = __builtin_amdgcn_rcpf(osum[reg]);
            if (allv || m < TOK) ob[(long)m * 128] = oacc[reg] * inv;
        }
    }
}

// ---------------- Proj GEMM: A staged in LDS, W fragment-coalesced global ---
template <bool A16>
__global__ __launch_bounds__(256, 4) void proj_mfma(
    const void* __restrict__ Ain,       // fp16 o16 or fp32 out
    const _Float16* __restrict__ w16,   // fragment-ordered proj weights
    const float* __restrict__ proj_b,   // [128]
    float* __restrict__ out,
    int totalRows)
{
    __shared__ __align__(16) _Float16 al[128 * 132];   // 33792 B -> 4 blocks/CU

    const int tid  = threadIdx.x;
    const int wv   = tid >> 6;
    const int lane = tid & 63;
    const int t32  = lane & 31;
    const int half = lane >> 5;

    // coalesced staging of this block's 128 A rows as fp16
#pragma unroll
    for (int it = 0; it < 8; ++it) {
        int j = it * 256 + tid;           // 128 rows x 16 chunks
        int row = j >> 4, c8 = (j & 15) << 3;
        long gr = (long)blockIdx.x * 128 + row;
        if (gr >= totalRows) gr = totalRows - 1;
        if (A16) {
            *(half8*)&al[row * 132 + c8] =
                *(const half8*)((const _Float16*)Ain + gr * 128 + c8);
        } else {
            const float* src = (const float*)Ain + gr * 128 + c8;
            float4 a0 = *(const float4*)src;
            float4 a1 = *(const float4*)(src + 4);
            *(half8*)&al[row * 132 + c8] = cvt8(a0, a1);
        }
    }
    __syncthreads();

    half8 af[8];
#pragma unroll
    for (int kt = 0; kt < 8; ++kt)
        af[kt] = *(const half8*)&al[(32 * wv + t32) * 132 + kt * 16 + half * 8];

    const _Float16* wb = w16 + lane * 8;   // + (nt*8+kt)*512

    f32x16 acc[4];
#pragma unroll
    for (int nt = 0; nt < 4; nt++)
#pragma unroll
        for (int i = 0; i < 16; i++) acc[nt][i] = 0.f;

#pragma unroll
    for (int kt = 0; kt < 8; ++kt) {
#pragma unroll
        for (int nt = 0; nt < 4; ++nt) {
            half8 bf = *(const half8*)(wb + (nt * 8 + kt) * 512);
            acc[nt] = __builtin_amdgcn_mfma_f32_32x32x16_f16(af[kt], bf, acc[nt], 0, 0, 0);
        }
    }

    const long rowb = (long)blockIdx.x * 128 + 32 * wv;
#pragma unroll
    for (int nt = 0; nt < 4; ++nt) {
        int co = nt * 32 + t32;
        float pb = proj_b[co];
#pragma unroll
        for (int reg = 0; reg < 16; ++reg) {
            long m = rowb + (reg & 3) + 8 * (reg >> 2) + 4 * half;
            if (m < totalRows) out[m * 128 + co] = acc[nt][reg] + pb;
        }
    }
}

extern "C" void kernel_launch(void* const* d_in, const int* in_sizes, int n_in,
                              void* d_out, int out_size, void* d_ws, size_t ws_size,
                              hipStream_t stream) {
    const float* x      = (const float*)d_in[0];
    const float* mask   = (const float*)d_in[1];
    const float* qkv_w  = (const float*)d_in[2];
    const float* qkv_b  = (const float*)d_in[3];
    const float* rel    = (const float*)d_in[4];
    const float* proj_w = (const float*)d_in[5];
    const float* proj_b = (const float*)d_in[6];
    float* out = (float*)d_out;

    const int B     = in_sizes[0] / (TOK * 128);
    const int Lmask = in_sizes[1] / (TOK * TOK);
    const int totalRows = B * TOK;

    // ws layout: w16 (65536 halves = 131072 B) | bias32 (4*98*112 f32 = 175616 B) | o16
    _Float16* w16    = (_Float16*)d_ws;
    float*    bias32 = (float*)((char*)d_ws + 131072);
    _Float16* o16    = (_Float16*)((char*)d_ws + 131072 + 175616);
    const size_t needO = 131072 + 175616 + (size_t)totalRows * 256;
    const int useO16 = (ws_size >= needO) ? 1 : 0;

    const int prepN = 65536 + 4 * 98 * BIAS_STR;
    prep_w<<<(prepN + 255) / 256, 256, 0, stream>>>(qkv_w, proj_w, rel, w16, bias32);

    attn_mfma<<<B * 4, 256, 0, stream>>>(x, mask, qkv_b, w16, bias32, out, o16,
                                         Lmask, useO16);

    const int grid = (totalRows + 127) / 128;
    if (useO16)
        proj_mfma<true><<<grid, 256, 0, stream>>>((const void*)o16, w16 + 49152,
                                                  proj_b, out, totalRows);
    else
        proj_mfma<false><<<grid, 256, 0, stream>>>((const void*)out, w16 + 49152,
                                                   proj_b, out, totalRows);
}

// Round 8
// 448.856 us; speedup vs baseline: 3.1701x; 1.3866x over previous
//
#include <hip/hip_runtime.h>

typedef __attribute__((ext_vector_type(8))) _Float16 half8;
typedef __attribute__((ext_vector_type(16))) float f32x16;

#define TOK 98
#define QSCALE 0.17677669529663687f  // 1/sqrt(32)

// LDS layout in _Float16 units — three overlaid phases:
//  Phase A (staging):     XL [98][132] at 0            (x as fp16)
//  Phase B (after bar#2): VT [32][132] at 0,  QS [98][40] at 4224, KS [98][40] at 8144
//  Phase C (after bar#4): PS [98][112] at 4224         (over dead Q,K)
// Total: 15200 halves = 30400 B + rel_lds 2028 B = 32428 B -> 5 blocks/CU
#define XL   0
#define XSTR 132
#define VT   0
#define VSTR 132
#define QS   4224
#define KS   8144
#define PS   4224
#define PSTR 112
#define LDSH 15200

__device__ inline half8 cvt8(float4 a, float4 b) {
    half8 r;
    r[0] = (_Float16)a.x; r[1] = (_Float16)a.y; r[2] = (_Float16)a.z; r[3] = (_Float16)a.w;
    r[4] = (_Float16)b.x; r[5] = (_Float16)b.y; r[6] = (_Float16)b.z; r[7] = (_Float16)b.w;
    return r;
}

// ---------------- Prep: fp32 -> fp16 weights in MFMA-FRAGMENT order ---------
// qkv region  [0..49152):  idx = (((h*3+nt)*8 + kt)*64 + lane)*8 + e
// proj region [49152..65536): idx = ((nt*8 + kt)*64 + lane)*8 + e
__global__ void prep_w(const float* __restrict__ qkv_w,
                       const float* __restrict__ proj_w,
                       _Float16* __restrict__ w16)
{
    int i = blockIdx.x * 256 + threadIdx.x;   // grid exactly 65536 threads
    if (i < 49152) {
        int e = i & 7, lane = (i >> 3) & 63, kt = (i >> 9) & 7;
        int g = i >> 12;                  // g = h*3 + nt, 0..11
        int h = g / 3, nt = g - 3 * h;
        int t32 = lane & 31, hf = lane >> 5;
        w16[i] = (_Float16)qkv_w[(nt * 128 + h * 32 + t32) * 128 + kt * 16 + hf * 8 + e];
    } else {
        int j = i - 49152;
        int e = j & 7, lane = (j >> 3) & 63, kt = (j >> 9) & 7, nt = j >> 12;
        int t32 = lane & 31, hf = lane >> 5;
        w16[i] = (_Float16)proj_w[(nt * 32 + t32) * 128 + kt * 16 + hf * 8 + e];
    }
}

__global__ __launch_bounds__(256, 5) void attn_mfma(
    const float* __restrict__ x,       // [B][98][128]
    const float* __restrict__ mask,    // [L][98][98]
    const float* __restrict__ qkv_b,   // [384]
    const float* __restrict__ rel,     // [4][507]
    const _Float16* __restrict__ qkv16,// fragment-ordered qkv weights
    float* __restrict__ out,           // [B][98][128] (pre-proj, fp32 path)
    _Float16* __restrict__ o16,        // [B][98][128] fp16 (ws path)
    int Lmask, int useO16)
{
    __shared__ __align__(16) _Float16 lh[LDSH];
    __shared__ float rel_lds[507];

    const int tid  = threadIdx.x;

    // XCD-bijective swizzle (grid % 8 == 0 in this problem).
    int wg = (int)blockIdx.x;
    int work;
    if ((gridDim.x & 7) == 0) {
        int cpx = gridDim.x >> 3;
        work = (wg & 7) * cpx + (wg >> 3);
    } else {
        work = wg;
    }
    const int b    = work >> 2;
    const int h    = work & 3;

    const int wv   = tid >> 6;        // wave 0..3: owns token rows [32wv, 32wv+32)
    const int lane = tid & 63;
    const int t32  = lane & 31;
    const int half = lane >> 5;

    // ---- stage rel row; stage x fp16 coalesced into XL ----
    for (int i = tid; i < 507; i += 256) rel_lds[i] = rel[h * 507 + i];
    for (int j = tid; j < TOK * 16; j += 256) {
        int row = j >> 4, c8 = (j & 15) << 3;
        const float* src = x + ((long)b * TOK + row) * 128 + c8;
        float4 a0 = *(const float4*)src;
        float4 a1 = *(const float4*)(src + 4);
        *(half8*)&lh[XL + row * XSTR + c8] = cvt8(a0, a1);
    }
    __syncthreads();   // bar #1: XL ready

    // ---- preload A fragments (all XL reads happen here) ----
    int tok = 32 * wv + t32; if (tok > 97) tok = 97;   // clamp: dup rows discarded

    half8 af[8];
#pragma unroll
    for (int kt = 0; kt < 8; ++kt)
        af[kt] = *(const half8*)&lh[XL + tok * XSTR + kt * 16 + half * 8];

    __syncthreads();   // bar #2: XL dead -> Q/K/Vt region may be written

    // ---------------- Stage 1: qkv slice GEMM (A regs, B fragment-coalesced) --
    const _Float16* wbase = qkv16 + (long)h * 3 * 4096 + lane * 8;  // + (nt*8+kt)*512

    f32x16 acc[3];
#pragma unroll
    for (int nt = 0; nt < 3; nt++)
#pragma unroll
        for (int i = 0; i < 16; i++) acc[nt][i] = 0.f;

#pragma unroll
    for (int kt = 0; kt < 8; ++kt) {
#pragma unroll
        for (int nt = 0; nt < 3; nt++) {
            half8 bf = *(const half8*)(wbase + (nt * 8 + kt) * 512);
            acc[nt] = __builtin_amdgcn_mfma_f32_32x32x16_f16(af[kt], bf, acc[nt], 0, 0, 0);
        }
    }

    // store Q (scaled+bias), K row-major; V transposed Vt[d][m].
    // C/D layout: col=lane&31, row=(reg&3)+8*(reg>>2)+4*half
    {
        const float qb = qkv_b[h * 32 + t32];
        const float kb = qkv_b[128 + h * 32 + t32];
        const float vb = qkv_b[256 + h * 32 + t32];
        const bool allv = (32 * wv + 31) < TOK;     // wave-uniform: rows all valid
        if (allv) {
#pragma unroll
            for (int reg = 0; reg < 16; ++reg) {
                int m = 32 * wv + (reg & 3) + 8 * (reg >> 2) + 4 * half;
                lh[QS + m * 40 + t32]   = (_Float16)((acc[0][reg] + qb) * QSCALE);
                lh[KS + m * 40 + t32]   = (_Float16)(acc[1][reg] + kb);
                lh[VT + t32 * VSTR + m] = (_Float16)(acc[2][reg] + vb);
            }
        } else {
#pragma unroll
            for (int reg = 0; reg < 16; ++reg) {
                int m = 32 * wv + (reg & 3) + 8 * (reg >> 2) + 4 * half;
                if (m < TOK) {
                    lh[QS + m * 40 + t32]   = (_Float16)((acc[0][reg] + qb) * QSCALE);
                    lh[KS + m * 40 + t32]   = (_Float16)(acc[1][reg] + kb);
                    lh[VT + t32 * VSTR + m] = (_Float16)(acc[2][reg] + vb);
                }
            }
        }
    }
    // zero Vt pad tokens 98..111 (PV k-padding) — VT region valid after bar#2
    for (int i = tid; i < 32 * 14; i += 256) {
        int d = i / 14, m = i - 14 * d;
        lh[VT + d * VSTR + 98 + m] = (_Float16)0.f;
    }

    // ---- mask burst: unconditional clamped loads (mv only — proven no-spill);
    //      latency hides under the bar#3 wait.
    const long mbase = (long)(b % Lmask) * (TOK * TOK);
    const int mrow0 = 32 * wv + 4 * half;

    int jterm[4]; bool jvld[4];
    float mv[4][16];
#pragma unroll
    for (int nt = 0; nt < 4; ++nt) {
        int j = nt * 32 + t32;
        jvld[nt] = (j < TOK);
        int jc = jvld[nt] ? j : 97;
        int tj = jc / 49; int rj = jc - 49 * tj; int hj = rj / 7; int wj = rj - 7 * hj;
        jterm[nt] = tj * 169 + hj * 13 + wj;
        const float* mc = mask + mbase + jc;
#pragma unroll
        for (int reg = 0; reg < 16; ++reg) {
            int m = mrow0 + (reg & 3) + 8 * (reg >> 2);
            int mm = m > 97 ? 97 : m;
            mv[nt][reg] = mc[(long)mm * TOK];
        }
    }

    __syncthreads();   // bar #3: Q/K/Vt visible; burst latency drains here

    // ---- init S accumulator with bias+mask+validity (MFMA C-input) ----------
    f32x16 sacc[4];
#pragma unroll
    for (int reg = 0; reg < 16; ++reg) {
        int m = mrow0 + (reg & 3) + 8 * (reg >> 2);
        bool mok = (m < TOK);
        int mm = mok ? m : 97;
        int ti = mm / 49; int r2 = mm - 49 * ti; int hi = r2 / 7; int wi = r2 - 7 * hi;
        // offset 253 = 1*169 + 6*13 + 6 so that mterm - jterm == REL_IDX[m][j]
        int mterm = ti * 169 + hi * 13 + wi + 253;
#pragma unroll
        for (int nt = 0; nt < 4; ++nt) {
            float s = -1e30f;
            if (mok && jvld[nt]) s = rel_lds[mterm - jterm[nt]] + mv[nt][reg];
            sacc[nt][reg] = s;
        }
    }

    // ---------------- Stage 2: S += Q K^T (accumulates onto bias init) -------
#pragma unroll
    for (int kk = 0; kk < 2; ++kk) {
        half8 qa = *(const half8*)&lh[QS + tok * 40 + kk * 16 + half * 8];
#pragma unroll
        for (int nt = 0; nt < 4; ++nt) {
            int kr = nt * 32 + t32; if (kr > 97) kr = 97;   // dup cols stay ~-1e30
            half8 kf = *(const half8*)&lh[KS + kr * 40 + kk * 16 + half * 8];
            sacc[nt] = __builtin_amdgcn_mfma_f32_32x32x16_f16(qa, kf, sacc[nt], 0, 0, 0);
        }
    }

    __syncthreads();   // bar #4: all Q/K reads done -> P may overlay them

    // ---------------- Stage 3: tile-max softmax ----------------
    float wm = -1e30f;
#pragma unroll
    for (int nt = 0; nt < 4; ++nt)
#pragma unroll
        for (int reg = 0; reg < 16; ++reg) wm = fmaxf(wm, sacc[nt][reg]);
    wm = fmaxf(wm, __shfl_xor(wm, 1));
    wm = fmaxf(wm, __shfl_xor(wm, 2));
    wm = fmaxf(wm, __shfl_xor(wm, 4));
    wm = fmaxf(wm, __shfl_xor(wm, 8));
    wm = fmaxf(wm, __shfl_xor(wm, 16));
    wm = fmaxf(wm, __shfl_xor(wm, 32));

#pragma unroll
    for (int nt = 0; nt < 4; ++nt) {
        int j = nt * 32 + t32;
#pragma unroll
        for (int reg = 0; reg < 16; ++reg) {
            int m = mrow0 + (reg & 3) + 8 * (reg >> 2);
            float p = __expf(sacc[nt][reg] - wm);
            if (m < TOK && j < 112) lh[PS + m * PSTR + j] = (_Float16)p; // pad cols -> exact 0
        }
    }

    // ---------------- Stage 4: O = P V ; row-sums via MFMA against ones ------
    f32x16 oacc, osum;
#pragma unroll
    for (int i = 0; i < 16; i++) { oacc[i] = 0.f; osum[i] = 0.f; }

    half8 vones;
#pragma unroll
    for (int i = 0; i < 8; ++i) vones[i] = (_Float16)1.0f;

#pragma unroll
    for (int kk = 0; kk < 7; ++kk) {
        half8 pa = *(const half8*)&lh[PS + tok * PSTR + kk * 16 + half * 8];
        half8 vf = *(const half8*)&lh[VT + t32 * VSTR + kk * 16 + half * 8];
        oacc = __builtin_amdgcn_mfma_f32_32x32x16_f16(pa, vf, oacc, 0, 0, 0);
        osum = __builtin_amdgcn_mfma_f32_32x32x16_f16(pa, vones, osum, 0, 0, 0);
    }

    const bool allv = (32 * wv + 31) < TOK;
    if (useO16) {
        _Float16* ob = o16 + ((long)b * TOK) * 128 + h * 32 + t32;
#pragma unroll
        for (int reg = 0; reg < 16; ++reg) {
            int m = mrow0 + (reg & 3) + 8 * (reg >> 2);
            float inv = __builtin_amdgcn_rcpf(osum[reg]);
            if (allv || m < TOK) ob[(long)m * 128] = (_Float16)(oacc[reg] * inv);
        }
    } else {
        float* ob = out + ((long)b * TOK) * 128 + h * 32 + t32;
#pragma unroll
        for (int reg = 0; reg < 16; ++reg) {
            int m = mrow0 + (reg & 3) + 8 * (reg >> 2);
            float inv = __builtin_amdgcn_rcpf(osum[reg]);
            if (allv || m < TOK) ob[(long)m * 128] = oacc[reg] * inv;
        }
    }
}

// ---------------- Proj GEMM: A staged in LDS, W fragment-coalesced global ---
template <bool A16>
__global__ __launch_bounds__(256, 4) void proj_mfma(
    const void* __restrict__ Ain,       // fp16 o16 or fp32 out
    const _Float16* __restrict__ w16,   // fragment-ordered proj weights
    const float* __restrict__ proj_b,   // [128]
    float* __restrict__ out,
    int totalRows)
{
    __shared__ __align__(16) _Float16 al[128 * 132];   // 33792 B -> 4 blocks/CU

    const int tid  = threadIdx.x;
    const int wv   = tid >> 6;
    const int lane = tid & 63;
    const int t32  = lane & 31;
    const int half = lane >> 5;

    // coalesced staging of this block's 128 A rows as fp16
#pragma unroll
    for (int it = 0; it < 8; ++it) {
        int j = it * 256 + tid;           // 128 rows x 16 chunks
        int row = j >> 4, c8 = (j & 15) << 3;
        long gr = (long)blockIdx.x * 128 + row;
        if (gr >= totalRows) gr = totalRows - 1;
        if (A16) {
            *(half8*)&al[row * 132 + c8] =
                *(const half8*)((const _Float16*)Ain + gr * 128 + c8);
        } else {
            const float* src = (const float*)Ain + gr * 128 + c8;
            float4 a0 = *(const float4*)src;
            float4 a1 = *(const float4*)(src + 4);
            *(half8*)&al[row * 132 + c8] = cvt8(a0, a1);
        }
    }
    __syncthreads();

    half8 af[8];
#pragma unroll
    for (int kt = 0; kt < 8; ++kt)
        af[kt] = *(const half8*)&al[(32 * wv + t32) * 132 + kt * 16 + half * 8];

    const _Float16* wb = w16 + lane * 8;   // + (nt*8+kt)*512

    f32x16 acc[4];
#pragma unroll
    for (int nt = 0; nt < 4; nt++)
#pragma unroll
        for (int i = 0; i < 16; i++) acc[nt][i] = 0.f;

#pragma unroll
    for (int kt = 0; kt < 8; ++kt) {
#pragma unroll
        for (int nt = 0; nt < 4; ++nt) {
            half8 bf = *(const half8*)(wb + (nt * 8 + kt) * 512);
            acc[nt] = __builtin_amdgcn_mfma_f32_32x32x16_f16(af[kt], bf, acc[nt], 0, 0, 0);
        }
    }

    const long rowb = (long)blockIdx.x * 128 + 32 * wv;
#pragma unroll
    for (int nt = 0; nt < 4; ++nt) {
        int co = nt * 32 + t32;
        float pb = proj_b[co];
#pragma unroll
        for (int reg = 0; reg < 16; ++reg) {
            long m = rowb + (reg & 3) + 8 * (reg >> 2) + 4 * half;
            if (m < totalRows) out[m * 128 + co] = acc[nt][reg] + pb;
        }
    }
}

extern "C" void kernel_launch(void* const* d_in, const int* in_sizes, int n_in,
                              void* d_out, int out_size, void* d_ws, size_t ws_size,
                              hipStream_t stream) {
    const float* x      = (const float*)d_in[0];
    const float* mask   = (const float*)d_in[1];
    const float* qkv_w  = (const float*)d_in[2];
    const float* qkv_b  = (const float*)d_in[3];
    const float* rel    = (const float*)d_in[4];
    const float* proj_w = (const float*)d_in[5];
    const float* proj_b = (const float*)d_in[6];
    float* out = (float*)d_out;

    const int B     = in_sizes[0] / (TOK * 128);
    const int Lmask = in_sizes[1] / (TOK * TOK);
    const int totalRows = B * TOK;

    // ws layout: w16 (65536 halves = 131072 B) | o16
    _Float16* w16  = (_Float16*)d_ws;
    _Float16* o16  = w16 + 65536;
    const size_t needO = 131072 + (size_t)totalRows * 256;
    const int useO16 = (ws_size >= needO) ? 1 : 0;

    prep_w<<<256, 256, 0, stream>>>(qkv_w, proj_w, w16);

    attn_mfma<<<B * 4, 256, 0, stream>>>(x, mask, qkv_b, rel, w16, out, o16,
                                         Lmask, useO16);

    const int grid = (totalRows + 127) / 128;
    if (useO16)
        proj_mfma<true><<<grid, 256, 0, stream>>>((const void*)o16, w16 + 49152,
                                                  proj_b, out, totalRows);
    else
        proj_mfma<false><<<grid, 256, 0, stream>>>((const void*)out, w16 + 49152,
                                                   proj_b, out, totalRows);
}

// Round 11
// 364.256 us; speedup vs baseline: 3.9064x; 1.2323x over previous
//
#include <hip/hip_runtime.h>

typedef __attribute__((ext_vector_type(8))) _Float16 half8;
typedef __attribute__((ext_vector_type(16))) float f32x16;

#define TOK 98
#define QSCALE 0.17677669529663687f  // 1/sqrt(32)

// LDS layout in _Float16 units — three overlaid phases (round-5 proven):
//  Phase A (staging):     XL [98][132] at 0            (x as fp16)
//  Phase B (after bar#2): VT [32][132] at 0,  QS [98][40] at 4224, KS [98][40] at 8144
//  Phase C (after bar#4): PS [98][120] at 4224         (over dead Q,K)
#define XL   0
#define XSTR 132
#define VT   0
#define VSTR 132
#define QS   4224
#define KS   8144
#define PS   4224
#define PSTR 120
#define LDSH 15984   // 31968 B + rel_lds 2028 B -> 4 blocks/CU, VGPR 60 proven

__device__ inline half8 cvt8(float4 a, float4 b) {
    half8 r;
    r[0] = (_Float16)a.x; r[1] = (_Float16)a.y; r[2] = (_Float16)a.z; r[3] = (_Float16)a.w;
    r[4] = (_Float16)b.x; r[5] = (_Float16)b.y; r[6] = (_Float16)b.z; r[7] = (_Float16)b.w;
    return r;
}

// ---------------- Prep: fp32 -> fp16 weights in MFMA-FRAGMENT order ---------
// qkv region  [0..49152):  idx = (((h*3+nt)*8 + kt)*64 + lane)*8 + e
// proj region [49152..65536): idx = ((nt*8 + kt)*64 + lane)*8 + e
__global__ void prep_w(const float* __restrict__ qkv_w,
                       const float* __restrict__ proj_w,
                       _Float16* __restrict__ w16)
{
    int i = blockIdx.x * 256 + threadIdx.x;   // grid exactly 65536 threads
    if (i < 49152) {
        int e = i & 7, lane = (i >> 3) & 63, kt = (i >> 9) & 7;
        int g = i >> 12;                  // g = h*3 + nt, 0..11
        int h = g / 3, nt = g - 3 * h;
        int t32 = lane & 31, hf = lane >> 5;
        w16[i] = (_Float16)qkv_w[(nt * 128 + h * 32 + t32) * 128 + kt * 16 + hf * 8 + e];
    } else {
        int j = i - 49152;
        int e = j & 7, lane = (j >> 3) & 63, kt = (j >> 9) & 7, nt = j >> 12;
        int t32 = lane & 31, hf = lane >> 5;
        w16[i] = (_Float16)proj_w[(nt * 32 + t32) * 128 + kt * 16 + hf * 8 + e];
    }
}

__global__ __launch_bounds__(256, 4) void attn_mfma(
    const float* __restrict__ x,       // [B][98][128]
    const float* __restrict__ mask,    // [L][98][98]
    const float* __restrict__ qkv_b,   // [384]
    const float* __restrict__ rel,     // [4][507]
    const _Float16* __restrict__ qkv16,// fragment-ordered qkv weights
    float* __restrict__ out,           // [B][98][128] (pre-proj, fp32 path)
    _Float16* __restrict__ o16,        // [B][98][128] fp16 (ws path)
    int Lmask, int useO16)
{
    __shared__ __align__(16) _Float16 lh[LDSH];
    __shared__ float rel_lds[507];

    const int tid  = threadIdx.x;

    // XCD-bijective swizzle (grid % 8 == 0 in this problem).
    int wg = (int)blockIdx.x;
    int work;
    if ((gridDim.x & 7) == 0) {
        int cpx = gridDim.x >> 3;
        work = (wg & 7) * cpx + (wg >> 3);
    } else {
        work = wg;
    }
    const int b    = work >> 2;
    const int h    = work & 3;

    const int wv   = tid >> 6;        // wave 0..3: owns token rows [32wv, 32wv+32)
    const int lane = tid & 63;
    const int t32  = lane & 31;
    const int half = lane >> 5;

    // ---- stage rel row; stage x fp16 coalesced into XL ----
    for (int i = tid; i < 507; i += 256) rel_lds[i] = rel[h * 507 + i];
    for (int j = tid; j < TOK * 16; j += 256) {
        int row = j >> 4, c8 = (j & 15) << 3;
        const float* src = x + ((long)b * TOK + row) * 128 + c8;
        float4 a0 = *(const float4*)src;
        float4 a1 = *(const float4*)(src + 4);
        *(half8*)&lh[XL + row * XSTR + c8] = cvt8(a0, a1);
    }
    __syncthreads();   // bar #1: XL ready

    // ---- preload A fragments (all XL reads happen here) ----
    int tok = 32 * wv + t32; if (tok > 97) tok = 97;   // clamp: dup rows discarded

    half8 af[8];
#pragma unroll
    for (int kt = 0; kt < 8; ++kt)
        af[kt] = *(const half8*)&lh[XL + tok * XSTR + kt * 16 + half * 8];

    __syncthreads();   // bar #2: XL dead -> Q/K/Vt region may be written

    // ---------------- Stage 1: qkv slice GEMM (A regs, B fragment-coalesced) --
    const _Float16* wbase = qkv16 + (long)h * 3 * 4096 + lane * 8;  // + (nt*8+kt)*512

    f32x16 acc[3];
#pragma unroll
    for (int nt = 0; nt < 3; nt++)
#pragma unroll
        for (int i = 0; i < 16; i++) acc[nt][i] = 0.f;

    __builtin_amdgcn_s_setprio(1);
#pragma unroll
    for (int kt = 0; kt < 8; ++kt) {
#pragma unroll
        for (int nt = 0; nt < 3; nt++) {
            half8 bf = *(const half8*)(wbase + (nt * 8 + kt) * 512);
            acc[nt] = __builtin_amdgcn_mfma_f32_32x32x16_f16(af[kt], bf, acc[nt], 0, 0, 0);
        }
    }
    __builtin_amdgcn_s_setprio(0);

    const bool allv = (32 * wv + 31) < TOK;     // wave-uniform: rows all valid

    // store Q (scaled+bias), K row-major; V transposed Vt[d][m].
    // C/D layout: col=lane&31, row=(reg&3)+8*(reg>>2)+4*half
    {
        const float qb = qkv_b[h * 32 + t32];
        const float kb = qkv_b[128 + h * 32 + t32];
        const float vb = qkv_b[256 + h * 32 + t32];
        if (allv) {
#pragma unroll
            for (int reg = 0; reg < 16; ++reg) {
                int m = 32 * wv + (reg & 3) + 8 * (reg >> 2) + 4 * half;
                lh[QS + m * 40 + t32]   = (_Float16)((acc[0][reg] + qb) * QSCALE);
                lh[KS + m * 40 + t32]   = (_Float16)(acc[1][reg] + kb);
                lh[VT + t32 * VSTR + m] = (_Float16)(acc[2][reg] + vb);
            }
        } else {
#pragma unroll
            for (int reg = 0; reg < 16; ++reg) {
                int m = 32 * wv + (reg & 3) + 8 * (reg >> 2) + 4 * half;
                if (m < TOK) {
                    lh[QS + m * 40 + t32]   = (_Float16)((acc[0][reg] + qb) * QSCALE);
                    lh[KS + m * 40 + t32]   = (_Float16)(acc[1][reg] + kb);
                    lh[VT + t32 * VSTR + m] = (_Float16)(acc[2][reg] + vb);
                }
            }
        }
    }
    // zero Vt pad tokens 98..111 (PV k-padding) — VT region valid after bar#2
    for (int i = tid; i < 32 * 14; i += 256) {
        int d = i / 14, m = i - 14 * d;
        lh[VT + d * VSTR + 98 + m] = (_Float16)0.f;
    }

    // ---- mask burst: unconditional clamped loads (mv only — proven no-spill);
    //      latency hides under the bar#3 wait.
    const long mbase = (long)(b % Lmask) * (TOK * TOK);
    const int mrow0 = 32 * wv + 4 * half;

    int jterm[4]; bool jvld[4];
    float mv[4][16];
#pragma unroll
    for (int nt = 0; nt < 4; ++nt) {
        int j = nt * 32 + t32;
        jvld[nt] = (j < TOK);
        int jc = jvld[nt] ? j : 97;
        int tj = jc / 49; int rj = jc - 49 * tj; int hj = rj / 7; int wj = rj - 7 * hj;
        jterm[nt] = tj * 169 + hj * 13 + wj;
        const float* mc = mask + mbase + jc;
#pragma unroll
        for (int reg = 0; reg < 16; ++reg) {
            int m = mrow0 + (reg & 3) + 8 * (reg >> 2);
            int mm = m > 97 ? 97 : m;
            mv[nt][reg] = mc[(long)mm * TOK];
        }
    }

    __syncthreads();   // bar #3: Q/K/Vt visible; burst latency drains here

    // ---- init S accumulator with bias+mask+validity (MFMA C-input) ----------
    f32x16 sacc[4];
#pragma unroll
    for (int reg = 0; reg < 16; ++reg) {
        int m = mrow0 + (reg & 3) + 8 * (reg >> 2);
        bool mok = (m < TOK);
        int mm = mok ? m : 97;
        int ti = mm / 49; int r2 = mm - 49 * ti; int hi = r2 / 7; int wi = r2 - 7 * hi;
        // offset 253 = 1*169 + 6*13 + 6 so that mterm - jterm == REL_IDX[m][j]
        int mterm = ti * 169 + hi * 13 + wi + 253;
#pragma unroll
        for (int nt = 0; nt < 4; ++nt) {
            float s = -1e30f;
            if (mok && jvld[nt]) s = rel_lds[mterm - jterm[nt]] + mv[nt][reg];
            sacc[nt][reg] = s;
        }
    }

    // ---------------- Stage 2: S += Q K^T (accumulates onto bias init) -------
    __builtin_amdgcn_s_setprio(1);
#pragma unroll
    for (int kk = 0; kk < 2; ++kk) {
        half8 qa = *(const half8*)&lh[QS + tok * 40 + kk * 16 + half * 8];
#pragma unroll
        for (int nt = 0; nt < 4; ++nt) {
            int kr = nt * 32 + t32; if (kr > 97) kr = 97;   // dup cols stay ~-1e30
            half8 kf = *(const half8*)&lh[KS + kr * 40 + kk * 16 + half * 8];
            sacc[nt] = __builtin_amdgcn_mfma_f32_32x32x16_f16(qa, kf, sacc[nt], 0, 0, 0);
        }
    }
    __builtin_amdgcn_s_setprio(0);

    __syncthreads();   // bar #4: all Q/K reads done -> P may overlay them

    // ---------------- Stage 3: tile-max softmax ----------------
    float wm = -1e30f;
#pragma unroll
    for (int nt = 0; nt < 4; ++nt)
#pragma unroll
        for (int reg = 0; reg < 16; ++reg) wm = fmaxf(wm, sacc[nt][reg]);
    wm = fmaxf(wm, __shfl_xor(wm, 1));
    wm = fmaxf(wm, __shfl_xor(wm, 2));
    wm = fmaxf(wm, __shfl_xor(wm, 4));
    wm = fmaxf(wm, __shfl_xor(wm, 8));
    wm = fmaxf(wm, __shfl_xor(wm, 16));
    wm = fmaxf(wm, __shfl_xor(wm, 32));

#pragma unroll
    for (int nt = 0; nt < 4; ++nt) {
        int j = nt * 32 + t32;
#pragma unroll
        for (int reg = 0; reg < 16; ++reg) {
            int m = mrow0 + (reg & 3) + 8 * (reg >> 2);
            float p = __expf(sacc[nt][reg] - wm);
            if (m < TOK && j < 112) lh[PS + m * PSTR + j] = (_Float16)p; // pad cols -> exact 0
        }
    }

    // ---------------- Stage 4: O = P V ; row-sums via MFMA against ones ------
    f32x16 oacc, osum;
#pragma unroll
    for (int i = 0; i < 16; i++) { oacc[i] = 0.f; osum[i] = 0.f; }

    half8 vones;
#pragma unroll
    for (int i = 0; i < 8; ++i) vones[i] = (_Float16)1.0f;

    __builtin_amdgcn_s_setprio(1);
#pragma unroll
    for (int kk = 0; kk < 7; ++kk) {
        half8 pa = *(const half8*)&lh[PS + tok * PSTR + kk * 16 + half * 8];
        half8 vf = *(const half8*)&lh[VT + t32 * VSTR + kk * 16 + half * 8];
        oacc = __builtin_amdgcn_mfma_f32_32x32x16_f16(pa, vf, oacc, 0, 0, 0);
        osum = __builtin_amdgcn_mfma_f32_32x32x16_f16(pa, vones, osum, 0, 0, 0);
    }
    __builtin_amdgcn_s_setprio(0);

    if (useO16) {
        _Float16* ob = o16 + ((long)b * TOK) * 128 + h * 32 + t32;
#pragma unroll
        for (int reg = 0; reg < 16; ++reg) {
            int m = mrow0 + (reg & 3) + 8 * (reg >> 2);
            float inv = __builtin_amdgcn_rcpf(osum[reg]);
            if (allv || m < TOK) ob[(long)m * 128] = (_Float16)(oacc[reg] * inv);
        }
    } else {
        float* ob = out + ((long)b * TOK) * 128 + h * 32 + t32;
#pragma unroll
        for (int reg = 0; reg < 16; ++reg) {
            int m = mrow0 + (reg & 3) + 8 * (reg >> 2);
            float inv = __builtin_amdgcn_rcpf(osum[reg]);
            if (allv || m < TOK) ob[(long)m * 128] = oacc[reg] * inv;
        }
    }
}

// ---------------- Proj GEMM: A staged in LDS, W fragment-coalesced global ---
template <bool A16>
__global__ __launch_bounds__(256, 4) void proj_mfma(
    const void* __restrict__ Ain,       // fp16 o16 or fp32 out
    const _Float16* __restrict__ w16,   // fragment-ordered proj weights
    const float* __restrict__ proj_b,   // [128]
    float* __restrict__ out,
    int totalRows)
{
    __shared__ __align__(16) _Float16 al[128 * 132];   // 33792 B -> 4 blocks/CU

    const int tid  = threadIdx.x;
    const int wv   = tid >> 6;
    const int lane = tid & 63;
    const int t32  = lane & 31;
    const int half = lane >> 5;

    // coalesced staging of this block's 128 A rows as fp16
#pragma unroll
    for (int it = 0; it < 8; ++it) {
        int j = it * 256 + tid;           // 128 rows x 16 chunks
        int row = j >> 4, c8 = (j & 15) << 3;
        long gr = (long)blockIdx.x * 128 + row;
        if (gr >= totalRows) gr = totalRows - 1;
        if (A16) {
            *(half8*)&al[row * 132 + c8] =
                *(const half8*)((const _Float16*)Ain + gr * 128 + c8);
        } else {
            const float* src = (const float*)Ain + gr * 128 + c8;
            float4 a0 = *(const float4*)src;
            float4 a1 = *(const float4*)(src + 4);
            *(half8*)&al[row * 132 + c8] = cvt8(a0, a1);
        }
    }
    __syncthreads();

    half8 af[8];
#pragma unroll
    for (int kt = 0; kt < 8; ++kt)
        af[kt] = *(const half8*)&al[(32 * wv + t32) * 132 + kt * 16 + half * 8];

    const _Float16* wb = w16 + lane * 8;   // + (nt*8+kt)*512

    f32x16 acc[4];
#pragma unroll
    for (int nt = 0; nt < 4; nt++)
#pragma unroll
        for (int i = 0; i < 16; i++) acc[nt][i] = 0.f;

    __builtin_amdgcn_s_setprio(1);
#pragma unroll
    for (int kt = 0; kt < 8; ++kt) {
#pragma unroll
        for (int nt = 0; nt < 4; ++nt) {
            half8 bf = *(const half8*)(wb + (nt * 8 + kt) * 512);
            acc[nt] = __builtin_amdgcn_mfma_f32_32x32x16_f16(af[kt], bf, acc[nt], 0, 0, 0);
        }
    }
    __builtin_amdgcn_s_setprio(0);

    const long rowb = (long)blockIdx.x * 128 + 32 * wv;
#pragma unroll
    for (int nt = 0; nt < 4; ++nt) {
        int co = nt * 32 + t32;
        float pb = proj_b[co];
#pragma unroll
        for (int reg = 0; reg < 16; ++reg) {
            long m = rowb + (reg & 3) + 8 * (reg >> 2) + 4 * half;
            if (m < totalRows) out[m * 128 + co] = acc[nt][reg] + pb;
        }
    }
}

extern "C" void kernel_launch(void* const* d_in, const int* in_sizes, int n_in,
                              void* d_out, int out_size, void* d_ws, size_t ws_size,
                              hipStream_t stream) {
    const float* x      = (const float*)d_in[0];
    const float* mask   = (const float*)d_in[1];
    const float* qkv_w  = (const float*)d_in[2];
    const float* qkv_b  = (const float*)d_in[3];
    const float* rel    = (const float*)d_in[4];
    const float* proj_w = (const float*)d_in[5];
    const float* proj_b = (const float*)d_in[6];
    float* out = (float*)d_out;

    const int B     = in_sizes[0] / (TOK * 128);
    const int Lmask = in_sizes[1] / (TOK * TOK);
    const int totalRows = B * TOK;

    // ws layout: w16 (65536 halves = 131072 B) | o16
    _Float16* w16  = (_Float16*)d_ws;
    _Float16* o16  = w16 + 65536;
    const size_t needO = 131072 + (size_t)totalRows * 256;
    const int useO16 = (ws_size >= needO) ? 1 : 0;

    prep_w<<<256, 256, 0, stream>>>(qkv_w, proj_w, w16);

    attn_mfma<<<B * 4, 256, 0, stream>>>(x, mask, qkv_b, rel, w16, out, o16,
                                         Lmask, useO16);

    const int grid = (totalRows + 127) / 128;
    if (useO16)
        proj_mfma<true><<<grid, 256, 0, stream>>>((const void*)o16, w16 + 49152,
                                                  proj_b, out, totalRows);
    else
        proj_mfma<false><<<grid, 256, 0, stream>>>((const void*)out, w16 + 49152,
                                                   proj_b, out, totalRows);
}